// Round 8
// baseline (378.489 us; speedup 1.0000x reference)
//
#include <hip/hip_runtime.h>
#include <math.h>

#define S_LEN 4096
#define DMODEL 1024
#define NHEADS 16
#define DHEAD 64

typedef unsigned short u16;
typedef short bf16x8 __attribute__((ext_vector_type(8)));
typedef float f32x4 __attribute__((ext_vector_type(4)));
typedef u16 u16x4 __attribute__((ext_vector_type(4)));
typedef u16 u16x8 __attribute__((ext_vector_type(8)));
typedef unsigned uint4v __attribute__((ext_vector_type(4)));

__device__ __forceinline__ u16 f2bf(float f) {
    unsigned u = __builtin_bit_cast(unsigned, f);
    u = (u + 0x7FFFu + ((u >> 16) & 1u)) >> 16;
    return (u16)u;
}
__device__ __forceinline__ float bf2f(u16 b) {
    return __builtin_bit_cast(float, ((unsigned)b) << 16);
}
// packed f32x2 -> bf16x2 (RNE, identical rounding to f2bf)
__device__ __forceinline__ unsigned cvtpk(float lo, float hi) {
    unsigned r;
    asm("v_cvt_pk_bf16_f32 %0, %1, %2" : "=v"(r) : "v"(lo), "v"(hi));
    return r;
}

// async global->LDS, 16B per lane; LDS dest = wave-uniform base + lane*16
__device__ __forceinline__ void gload16(const void* g, void* l) {
    __builtin_amdgcn_global_load_lds((const __attribute__((address_space(1))) void*)g,
                                     (__attribute__((address_space(3))) void*)l, 16, 0, 0);
}

// ---------------- RoPE tables (fp32-faithful to numpy float32 path) ----------------
__global__ void rope_table_kernel(float* __restrict__ cost, float* __restrict__ sint) {
    int tid = blockIdx.x * blockDim.x + threadIdx.x;  // 4096*32
    int i = tid & 31;
    int pos = tid >> 5;
    double e = (double)(2 * i) / 64.0;
    float t32 = (float)pow(10000.0, e);
    float freq = 1.0f / t32;
    float ang = (float)pos * freq;
    cost[tid] = (float)cos((double)ang);
    sint[tid] = (float)sin((double)ang);
}

// ---------------- fp32 -> bf16 hi (+ optional lo residual) ----------------
__global__ void split_kernel(const float* __restrict__ in, u16* __restrict__ hi,
                             u16* __restrict__ lo, int n4) {
    int i = blockIdx.x * blockDim.x + threadIdx.x;
    if (i >= n4) return;
    float4 v = ((const float4*)in)[i];
    float f[4] = {v.x, v.y, v.z, v.w};
    u16x4 h, l;
#pragma unroll
    for (int j = 0; j < 4; j++) {
        h[j] = f2bf(f[j]);
        l[j] = f2bf(f[j] - bf2f(h[j]));
    }
    ((u16x4*)hi)[i] = h;
    if (lo) ((u16x4*)lo)[i] = l;
}

// ---------------- QKV GEMM (pre-split bf16 inputs) + fused RoPE ----------------
// z=0 -> Q2 bf16 hi/lo [h][s][128] (RoPE, pre-scaled log2e/8); z=1 -> K2; z=2 -> V^T.
__global__ __launch_bounds__(256) void gemm_qkv_kernel(
        const u16* __restrict__ xh, const u16* __restrict__ xl,
        const u16* __restrict__ wh3, const u16* __restrict__ wl3,
        const int* __restrict__ tp,
        const float* __restrict__ cost, const float* __restrict__ sint,
        u16* __restrict__ q2, u16* __restrict__ k2, u16* __restrict__ vtb) {
    __shared__ u16 sAH[128 * 32], sAL[128 * 32], sBH[128 * 32], sBL[128 * 32];
    const int z = blockIdx.z;
    const u16* BH = wh3 + (size_t)z * 1048576;
    const u16* BL = wl3 + (size_t)z * 1048576;
    const int m0 = blockIdx.y * 128, n0 = blockIdx.x * 128;

    const int tid = threadIdx.x;
    const int lane = tid & 63, wid = tid >> 6;
    const int wr = wid >> 1, wc = wid & 1;
    const int l15 = lane & 15, lhi = lane >> 4;

    f32x4 acc[4][4];
#pragma unroll
    for (int i = 0; i < 4; i++)
#pragma unroll
        for (int j = 0; j < 4; j++) acc[i][j] = (f32x4){0.f, 0.f, 0.f, 0.f};

    for (int kt = 0; kt < 1024; kt += 32) {
#pragma unroll
        for (int i = 0; i < 2; i++) {
            const int rbase = wid * 32 + i * 16;
            const int row = rbase + (lane >> 2);
            const size_t aoff = (size_t)(m0 + row) * 1024 + kt + (lane & 3) * 8;
            const size_t boff = (size_t)(n0 + row) * 1024 + kt + (lane & 3) * 8;
            gload16(xh + aoff, sAH + rbase * 32);
            gload16(xl + aoff, sAL + rbase * 32);
            gload16(BH + boff, sBH + rbase * 32);
            gload16(BL + boff, sBL + rbase * 32);
        }
        __syncthreads();
        bf16x8 ah[4], al[4], bh[4], bl[4];
#pragma unroll
        for (int m = 0; m < 4; m++) {
            int row = wr * 64 + m * 16 + l15;
            ah[m] = *(const bf16x8*)(sAH + row * 32 + 8 * lhi);
            al[m] = *(const bf16x8*)(sAL + row * 32 + 8 * lhi);
        }
#pragma unroll
        for (int n = 0; n < 4; n++) {
            int row = wc * 64 + n * 16 + l15;
            bh[n] = *(const bf16x8*)(sBH + row * 32 + 8 * lhi);
            bl[n] = *(const bf16x8*)(sBL + row * 32 + 8 * lhi);
        }
#pragma unroll
        for (int m = 0; m < 4; m++)
#pragma unroll
            for (int n = 0; n < 4; n++) {
                acc[m][n] = __builtin_amdgcn_mfma_f32_16x16x32_bf16(al[m], bh[n], acc[m][n], 0, 0, 0);
                acc[m][n] = __builtin_amdgcn_mfma_f32_16x16x32_bf16(ah[m], bl[n], acc[m][n], 0, 0, 0);
                acc[m][n] = __builtin_amdgcn_mfma_f32_16x16x32_bf16(ah[m], bh[n], acc[m][n], 0, 0, 0);
            }
        __syncthreads();
    }

    if (z == 2) {
#pragma unroll
        for (int m = 0; m < 4; m++)
#pragma unroll
            for (int n = 0; n < 4; n++)
#pragma unroll
                for (int j = 0; j < 4; j++) {
                    int srow = m0 + wr * 64 + m * 16 + lhi * 4 + j;
                    int eg = n0 + wc * 64 + n * 16 + l15;
                    vtb[(size_t)eg * S_LEN + srow] = f2bf(acc[m][n][j]);
                }
        return;
    }

    u16* outp = (z == 0) ? q2 : k2;
    // fold 1/sqrt(64) AND log2(e) into Q so softmax can use native exp2
    const float qscale = (z == 0) ? 0.125f * 1.44269504088896340736f : 1.0f;
    const int head = (n0 + wc * 64) >> 6;
#pragma unroll
    for (int m = 0; m < 4; m++)
#pragma unroll
        for (int n = 0; n < 4; n++) {
            const int dh = n * 16 + l15;
            const int pairi = dh >> 1;
            const bool even = (dh & 1) == 0;
#pragma unroll
            for (int j = 0; j < 4; j++) {
                int srow = m0 + wr * 64 + m * 16 + lhi * 4 + j;
                float v = acc[m][n][j];
                float pv = __shfl_xor(v, 1);
                int pos = tp[srow];
                float cc = cost[(size_t)pos * 32 + pairi];
                float ss = sint[(size_t)pos * 32 + pairi];
                float e = even ? v : pv;
                float o = even ? pv : v;
                float res = (even ? (e * cc - o * ss) : (e * ss + o * cc)) * qscale;
                u16 hb = f2bf(res);
                u16 lb = f2bf(res - bf2f(hb));
                size_t base = ((size_t)head * S_LEN + srow) * 128 + dh;
                outp[base] = hb;
                outp[base + 64] = lb;
            }
        }
}

// ---------------- Flash attention: paired q-tiles + LDS K/V dbuf; base-2 softmax ----------------
#define PLD32 33
__global__ __launch_bounds__(256) void attn_kernel(const u16* __restrict__ q2,
                                                   const u16* __restrict__ k2,
                                                   const u16* __restrict__ vtb,
                                                   u16* __restrict__ attnb) {
    const int h = blockIdx.y;
    const int p = blockIdx.x;              // pair id 0..15 -> tiles (31-p, p)
    const int wid = threadIdx.x >> 6;
    const int lane = threadIdx.x & 63;
    const int l15 = lane & 15, lhi = lane >> 4;

    const u16* Qh2 = q2 + (size_t)h * S_LEN * 128;
    const u16* Kh2 = k2 + (size_t)h * S_LEN * 128;
    const u16* Vh  = vtb + (size_t)h * 64 * S_LEN;

    __shared__ u16 sK[2][64 * 128];
    __shared__ u16 sV[2][64 * 64];
    __shared__ unsigned pls[4][32 * PLD32];
    unsigned* myP = pls[wid];

    const int tileA = 31 - p, tileB = p;
    const int eA = 2 * tileA + 2, eB = 2 * tileB + 2;
    const int etot = eA + eB;              // 66 for every block

    auto stage = [&](int t, int b) {
        const int k = (t < eA) ? t : (t - eA);
        const int k0 = k * 64;
#pragma unroll
        for (int i = 0; i < 4; i++) {
            const int rbase = wid * 16 + i * 4;
            const int row = rbase + (lane >> 4);
            const int cb = (lane & 15) * 16;
            const int csw = cb ^ ((row & 7) << 4);
            gload16(Kh2 + (size_t)(k0 + row) * 128 + (csw >> 1), &sK[b][rbase * 128]);
        }
#pragma unroll
        for (int i = 0; i < 2; i++) {
            const int rbase = wid * 16 + i * 8;
            const int row = rbase + (lane >> 3);
            const int cb = (lane & 7) * 16;
            const int csw = cb ^ ((row & 7) << 4);
            gload16(Vh + (size_t)row * S_LEN + k0 + (csw >> 1), &sV[b][rbase * 64]);
        }
    };

    bf16x8 qhf[2][2], qlf[2][2];
    f32x4 oT[2][4];
    float m_run[2], l_run[2];
    int q0 = 0, my_nkb = 0;

    auto initPass = [&](int tile) {
        q0 = tile * 128 + wid * 32;
        my_nkb = ((q0 + 31) >> 6) + 1;
#pragma unroll
        for (int g = 0; g < 2; g++)
#pragma unroll
            for (int ks = 0; ks < 2; ks++) {
                const u16* qp = Qh2 + (size_t)(q0 + g * 16 + l15) * 128 + ks * 32 + 8 * lhi;
                qhf[g][ks] = *(const bf16x8*)(qp);
                qlf[g][ks] = *(const bf16x8*)(qp + 64);
            }
#pragma unroll
        for (int g = 0; g < 2; g++) {
            m_run[g] = -1e30f;
            l_run[g] = 0.f;
#pragma unroll
            for (int m = 0; m < 4; m++) oT[g][m] = (f32x4){0.f, 0.f, 0.f, 0.f};
        }
    };

    auto writeOut = [&]() {
#pragma unroll
        for (int g = 0; g < 2; g++) {
            const int srow = q0 + g * 16 + l15;
            const float inv = 1.0f / l_run[g];
#pragma unroll
            for (int m = 0; m < 4; m++)
#pragma unroll
                for (int j = 0; j < 4; j++)
                    attnb[(size_t)srow * 1024 + h * 64 + m * 16 + lhi * 4 + j] =
                        f2bf(oT[g][m][j] * inv);
        }
    };

    stage(0, 0);
    initPass(tileA);
    __syncthreads();

    int cur = 0;
    for (int t = 0; t < etot; ++t) {
        if (t + 1 < etot) stage(t + 1, cur ^ 1);
        if (t == eA) { writeOut(); initPass(tileB); }
        const int k = (t < eA) ? t : (t - eA);
        if (k < my_nkb) {
            const int k0 = k * 64;
            bf16x8 kh[4][2], kl[4][2], vfr[4][2];
#pragma unroll
            for (int m = 0; m < 4; m++) {
                const int r = m * 16 + l15;
                const int sw = (r & 7) << 4;
                const u16* kp = &sK[cur][r * 128];
                const u16* vp = &sV[cur][r * 64];
#pragma unroll
                for (int c = 0; c < 2; c++) {
                    kh[m][c] = *(const bf16x8*)(kp + (((c * 64 + lhi * 16) ^ sw) >> 1));
                    kl[m][c] = *(const bf16x8*)(kp + (((128 + c * 64 + lhi * 16) ^ sw) >> 1));
                    vfr[m][c] = *(const bf16x8*)(vp + (((c * 64 + lhi * 16) ^ sw) >> 1));
                }
            }
            f32x4 sT[4][2];
            __builtin_amdgcn_s_setprio(1);
#pragma unroll
            for (int m = 0; m < 4; m++)
#pragma unroll
                for (int g = 0; g < 2; g++) {
                    f32x4 a = (f32x4){0.f, 0.f, 0.f, 0.f};
                    a = __builtin_amdgcn_mfma_f32_16x16x32_bf16(kh[m][0], qlf[g][0], a, 0, 0, 0);
                    a = __builtin_amdgcn_mfma_f32_16x16x32_bf16(kh[m][1], qlf[g][1], a, 0, 0, 0);
                    a = __builtin_amdgcn_mfma_f32_16x16x32_bf16(kl[m][0], qhf[g][0], a, 0, 0, 0);
                    a = __builtin_amdgcn_mfma_f32_16x16x32_bf16(kl[m][1], qhf[g][1], a, 0, 0, 0);
                    a = __builtin_amdgcn_mfma_f32_16x16x32_bf16(kh[m][0], qhf[g][0], a, 0, 0, 0);
                    a = __builtin_amdgcn_mfma_f32_16x16x32_bf16(kh[m][1], qhf[g][1], a, 0, 0, 0);
                    sT[m][g] = a;
                }
            __builtin_amdgcn_s_setprio(0);
            const bool last = (k == my_nkb - 1);
#pragma unroll
            for (int g = 0; g < 2; g++) {
                const int qg = q0 + g * 16 + l15;
                if (last) {
#pragma unroll
                    for (int m = 0; m < 4; m++)
#pragma unroll
                        for (int j = 0; j < 4; j++) {
                            int kg = k0 + m * 16 + lhi * 4 + j;
                            if (kg > qg) sT[m][g][j] = -1e30f;
                        }
                }
                float t0 = fmaxf(fmaxf(sT[0][g][0], sT[0][g][1]), fmaxf(sT[0][g][2], sT[0][g][3]));
                float t1 = fmaxf(fmaxf(sT[1][g][0], sT[1][g][1]), fmaxf(sT[1][g][2], sT[1][g][3]));
                float t2 = fmaxf(fmaxf(sT[2][g][0], sT[2][g][1]), fmaxf(sT[2][g][2], sT[2][g][3]));
                float t3 = fmaxf(fmaxf(sT[3][g][0], sT[3][g][1]), fmaxf(sT[3][g][2], sT[3][g][3]));
                float mx = fmaxf(fmaxf(t0, t1), fmaxf(t2, t3));
                mx = fmaxf(mx, __shfl_xor(mx, 16));
                mx = fmaxf(mx, __shfl_xor(mx, 32));
                const float mo = m_run[g];
                const float mn = fmaxf(mo, mx);
                // base-2 online softmax (log2e folded into Q)
                float s0 = 0.f, s1 = 0.f, s2 = 0.f, s3 = 0.f;
#pragma unroll
                for (int m = 0; m < 4; m++) {
                    float p0 = exp2f(sT[m][g][0] - mn);
                    float p1 = exp2f(sT[m][g][1] - mn);
                    float p2 = exp2f(sT[m][g][2] - mn);
                    float p3 = exp2f(sT[m][g][3] - mn);
                    sT[m][g][0] = p0; sT[m][g][1] = p1; sT[m][g][2] = p2; sT[m][g][3] = p3;
                    s0 += p0; s1 += p1; s2 += p2; s3 += p3;
                }
                float rs = (s0 + s1) + (s2 + s3);
                rs += __shfl_xor(rs, 16);
                rs += __shfl_xor(rs, 32);
                if (__any(mn > mo)) {    // rescale only if some row's max grew (exact: alpha==1 otherwise)
                    float alpha = exp2f(mo - mn);
#pragma unroll
                    for (int m = 0; m < 4; m++) {
                        oT[g][m][0] *= alpha; oT[g][m][1] *= alpha;
                        oT[g][m][2] *= alpha; oT[g][m][3] *= alpha;
                    }
                    l_run[g] = l_run[g] * alpha + rs;
                    m_run[g] = mn;
                } else {
                    l_run[g] += rs;
                }
#pragma unroll
                for (int m = 0; m < 4; m++)
#pragma unroll
                    for (int jj = 0; jj < 2; jj++)
                        myP[(g * 16 + l15) * PLD32 + m * 8 + lhi * 2 + jj] =
                            cvtpk(sT[m][g][2 * jj], sT[m][g][2 * jj + 1]);
            }
            bf16x8 pf[2][2];
#pragma unroll
            for (int g = 0; g < 2; g++)
#pragma unroll
                for (int ks = 0; ks < 2; ks++) {
                    uint4v pw = *(const uint4v*)(myP + (g * 16 + l15) * PLD32 + ks * 16 + 4 * lhi);
                    pf[g][ks] = __builtin_bit_cast(bf16x8, pw);
                }
            __builtin_amdgcn_s_setprio(1);
#pragma unroll
            for (int g = 0; g < 2; g++)
#pragma unroll
                for (int m = 0; m < 4; m++) {
                    oT[g][m] = __builtin_amdgcn_mfma_f32_16x16x32_bf16(vfr[m][0], pf[g][0], oT[g][m], 0, 0, 0);
                    oT[g][m] = __builtin_amdgcn_mfma_f32_16x16x32_bf16(vfr[m][1], pf[g][1], oT[g][m], 0, 0, 0);
                }
            __builtin_amdgcn_s_setprio(0);
        }
        __syncthreads();
        cur ^= 1;
    }
    writeOut();
}

// ---------------- output projection: bf16 x bf16 -> fp32, gload16-staged ----------------
__global__ __launch_bounds__(256) void gemm_out_kernel(const u16* __restrict__ attnb,
                                                       const u16* __restrict__ woh,
                                                       float* __restrict__ out) {
    __shared__ u16 sA[128 * 32];
    __shared__ u16 sB[128 * 32];
    const int m0 = blockIdx.y * 128, n0 = blockIdx.x * 128;
    const int tid = threadIdx.x;
    const int lane = tid & 63, wid = tid >> 6;
    const int wr = wid >> 1, wc = wid & 1;
    const int l15 = lane & 15, lhi = lane >> 4;

    f32x4 acc[4][4];
#pragma unroll
    for (int i = 0; i < 4; i++)
#pragma unroll
        for (int j = 0; j < 4; j++) acc[i][j] = (f32x4){0.f, 0.f, 0.f, 0.f};

    for (int kt = 0; kt < 1024; kt += 32) {
#pragma unroll
        for (int i = 0; i < 2; i++) {
            const int rbase = wid * 32 + i * 16;
            const int row = rbase + (lane >> 2);
            gload16(attnb + (size_t)(m0 + row) * 1024 + kt + (lane & 3) * 8, sA + rbase * 32);
            gload16(woh + (size_t)(n0 + row) * 1024 + kt + (lane & 3) * 8, sB + rbase * 32);
        }
        __syncthreads();
        bf16x8 af[4], bfr[4];
#pragma unroll
        for (int m = 0; m < 4; m++) {
            int row = wr * 64 + m * 16 + l15;
            af[m] = *(const bf16x8*)(sA + row * 32 + 8 * lhi);
        }
#pragma unroll
        for (int n = 0; n < 4; n++) {
            int row = wc * 64 + n * 16 + l15;
            bfr[n] = *(const bf16x8*)(sB + row * 32 + 8 * lhi);
        }
#pragma unroll
        for (int m = 0; m < 4; m++)
#pragma unroll
            for (int n = 0; n < 4; n++)
                acc[m][n] = __builtin_amdgcn_mfma_f32_16x16x32_bf16(af[m], bfr[n], acc[m][n], 0, 0, 0);
        __syncthreads();
    }

#pragma unroll
    for (int m = 0; m < 4; m++)
#pragma unroll
        for (int n = 0; n < 4; n++)
#pragma unroll
            for (int j = 0; j < 4; j++) {
                int srow = m0 + wr * 64 + m * 16 + lhi * 4 + j;
                int eg = n0 + wc * 64 + n * 16 + l15;
                out[(size_t)srow * 1024 + eg] = acc[m][n][j];
            }
}

// ---------------- host launch ----------------
extern "C" void kernel_launch(void* const* d_in, const int* in_sizes, int n_in,
                              void* d_out, int out_size, void* d_ws, size_t ws_size,
                              hipStream_t stream) {
    const float* x = (const float*)d_in[0];
    const int* tp = (const int*)d_in[1];
    const float* wq = (const float*)d_in[2];
    const float* wk = (const float*)d_in[3];
    const float* wv = (const float*)d_in[4];
    const float* wo = (const float*)d_in[5];
    float* out = (float*)d_out;
    char* ws = (char*)d_ws;

    u16* Q2    = (u16*)(ws + 0);           // 16 MiB bf16 [16][4096][128] hi/lo, Q scaled log2e/8
    u16* K2    = (u16*)(ws + 16777216);    // 16 MiB
    u16* VTB   = (u16*)(ws + 33554432);    // 8 MiB bf16 [h*64+dh][4096]
    u16* ATTNB = (u16*)(ws + 41943040);    // 8 MiB bf16 [4096][1024]
    float* COST = (float*)(ws + 50331648); // 512 KiB
    float* SINT = (float*)(ws + 50855936); // 512 KiB
    u16* XH  = (u16*)(ws + 51380224);      // 8 MiB bf16 [4096][1024]
    u16* XL  = (u16*)(ws + 59768832);      // 8 MiB
    u16* WH3 = (u16*)(ws + 68157440);      // 6 MiB bf16 [3][1024][1024]
    u16* WL3 = (u16*)(ws + 74448896);      // 6 MiB
    u16* WOH = (u16*)(ws + 80740352);      // 2 MiB bf16 [1024][1024]

    rope_table_kernel<<<512, 256, 0, stream>>>(COST, SINT);

    split_kernel<<<4096, 256, 0, stream>>>(x, XH, XL, 1048576);
    split_kernel<<<1024, 256, 0, stream>>>(wq, WH3,            WL3,            262144);
    split_kernel<<<1024, 256, 0, stream>>>(wk, WH3 + 1048576,  WL3 + 1048576,  262144);
    split_kernel<<<1024, 256, 0, stream>>>(wv, WH3 + 2097152,  WL3 + 2097152,  262144);
    split_kernel<<<1024, 256, 0, stream>>>(wo, WOH,            (u16*)nullptr,  262144);

    gemm_qkv_kernel<<<dim3(8, 32, 3), 256, 0, stream>>>(
        XH, XL, WH3, WL3, tp, COST, SINT, Q2, K2, VTB);

    attn_kernel<<<dim3(16, 16), 256, 0, stream>>>(Q2, K2, VTB, ATTNB);

    gemm_out_kernel<<<dim3(8, 32), 256, 0, stream>>>(ATTNB, WOH, out);
}

// Round 9
// 337.642 us; speedup vs baseline: 1.1210x; 1.1210x over previous
//
#include <hip/hip_runtime.h>
#include <math.h>

#define S_LEN 4096
#define DMODEL 1024
#define NHEADS 16
#define DHEAD 64

typedef unsigned short u16;
typedef short bf16x8 __attribute__((ext_vector_type(8)));
typedef float f32x4 __attribute__((ext_vector_type(4)));
typedef u16 u16x4 __attribute__((ext_vector_type(4)));
typedef u16 u16x8 __attribute__((ext_vector_type(8)));
typedef unsigned uint4v __attribute__((ext_vector_type(4)));

__device__ __forceinline__ u16 f2bf(float f) {
    unsigned u = __builtin_bit_cast(unsigned, f);
    u = (u + 0x7FFFu + ((u >> 16) & 1u)) >> 16;
    return (u16)u;
}
__device__ __forceinline__ float bf2f(u16 b) {
    return __builtin_bit_cast(float, ((unsigned)b) << 16);
}

// async global->LDS, 16B per lane; LDS dest = wave-uniform base + lane*16
__device__ __forceinline__ void gload16(const void* g, void* l) {
    __builtin_amdgcn_global_load_lds((const __attribute__((address_space(1))) void*)g,
                                     (__attribute__((address_space(3))) void*)l, 16, 0, 0);
}

// ---------------- RoPE tables (fp32-faithful to numpy float32 path) ----------------
__global__ void rope_table_kernel(float* __restrict__ cost, float* __restrict__ sint) {
    int tid = blockIdx.x * blockDim.x + threadIdx.x;  // 4096*32
    int i = tid & 31;
    int pos = tid >> 5;
    double e = (double)(2 * i) / 64.0;
    float t32 = (float)pow(10000.0, e);
    float freq = 1.0f / t32;
    float ang = (float)pos * freq;
    cost[tid] = (float)cos((double)ang);
    sint[tid] = (float)sin((double)ang);
}

// ---------------- fp32 -> bf16 hi (+ optional lo residual) ----------------
__global__ void split_kernel(const float* __restrict__ in, u16* __restrict__ hi,
                             u16* __restrict__ lo, int n4) {
    int i = blockIdx.x * blockDim.x + threadIdx.x;
    if (i >= n4) return;
    float4 v = ((const float4*)in)[i];
    float f[4] = {v.x, v.y, v.z, v.w};
    u16x4 h, l;
#pragma unroll
    for (int j = 0; j < 4; j++) {
        h[j] = f2bf(f[j]);
        l[j] = f2bf(f[j] - bf2f(h[j]));
    }
    ((u16x4*)hi)[i] = h;
    if (lo) ((u16x4*)lo)[i] = l;
}

// ---------------- QKV GEMM (pre-split bf16, LDS double-buffer prefetch) + fused RoPE ----------------
// z=0 -> Q2 bf16 hi/lo [h][s][128] (RoPE, pre-scaled log2e/8); z=1 -> K2; z=2 -> V^T.
__global__ __launch_bounds__(256) void gemm_qkv_kernel(
        const u16* __restrict__ xh, const u16* __restrict__ xl,
        const u16* __restrict__ wh3, const u16* __restrict__ wl3,
        const int* __restrict__ tp,
        const float* __restrict__ cost, const float* __restrict__ sint,
        u16* __restrict__ q2, u16* __restrict__ k2, u16* __restrict__ vtb) {
    __shared__ u16 sAH[2][128 * 32], sAL[2][128 * 32], sBH[2][128 * 32], sBL[2][128 * 32];
    const int z = blockIdx.z;
    const u16* BH = wh3 + (size_t)z * 1048576;
    const u16* BL = wl3 + (size_t)z * 1048576;
    const int m0 = blockIdx.y * 128, n0 = blockIdx.x * 128;

    const int tid = threadIdx.x;
    const int lane = tid & 63, wid = tid >> 6;
    const int wr = wid >> 1, wc = wid & 1;
    const int l15 = lane & 15, lhi = lane >> 4;

    f32x4 acc[4][4];
#pragma unroll
    for (int i = 0; i < 4; i++)
#pragma unroll
        for (int j = 0; j < 4; j++) acc[i][j] = (f32x4){0.f, 0.f, 0.f, 0.f};

    auto stageT = [&](int kt, int b) {
#pragma unroll
        for (int i = 0; i < 2; i++) {
            const int rbase = wid * 32 + i * 16;
            const int row = rbase + (lane >> 2);
            const size_t aoff = (size_t)(m0 + row) * 1024 + kt + (lane & 3) * 8;
            const size_t boff = (size_t)(n0 + row) * 1024 + kt + (lane & 3) * 8;
            gload16(xh + aoff, sAH[b] + rbase * 32);
            gload16(xl + aoff, sAL[b] + rbase * 32);
            gload16(BH + boff, sBH[b] + rbase * 32);
            gload16(BL + boff, sBL[b] + rbase * 32);
        }
    };

    stageT(0, 0);
    __syncthreads();

    int buf = 0;
    for (int kt = 0; kt < 1024; kt += 32, buf ^= 1) {
        if (kt + 32 < 1024) stageT(kt + 32, buf ^ 1);   // prefetch next K-tile
        bf16x8 ah[4], al[4], bh[4], bl[4];
#pragma unroll
        for (int m = 0; m < 4; m++) {
            int row = wr * 64 + m * 16 + l15;
            ah[m] = *(const bf16x8*)(sAH[buf] + row * 32 + 8 * lhi);
            al[m] = *(const bf16x8*)(sAL[buf] + row * 32 + 8 * lhi);
        }
#pragma unroll
        for (int n = 0; n < 4; n++) {
            int row = wc * 64 + n * 16 + l15;
            bh[n] = *(const bf16x8*)(sBH[buf] + row * 32 + 8 * lhi);
            bl[n] = *(const bf16x8*)(sBL[buf] + row * 32 + 8 * lhi);
        }
#pragma unroll
        for (int m = 0; m < 4; m++)
#pragma unroll
            for (int n = 0; n < 4; n++) {
                acc[m][n] = __builtin_amdgcn_mfma_f32_16x16x32_bf16(al[m], bh[n], acc[m][n], 0, 0, 0);
                acc[m][n] = __builtin_amdgcn_mfma_f32_16x16x32_bf16(ah[m], bl[n], acc[m][n], 0, 0, 0);
                acc[m][n] = __builtin_amdgcn_mfma_f32_16x16x32_bf16(ah[m], bh[n], acc[m][n], 0, 0, 0);
            }
        __syncthreads();   // drains vmcnt: next buffer staged; this buffer free for re-stage
    }

    if (z == 2) {
#pragma unroll
        for (int m = 0; m < 4; m++)
#pragma unroll
            for (int n = 0; n < 4; n++)
#pragma unroll
                for (int j = 0; j < 4; j++) {
                    int srow = m0 + wr * 64 + m * 16 + lhi * 4 + j;
                    int eg = n0 + wc * 64 + n * 16 + l15;
                    vtb[(size_t)eg * S_LEN + srow] = f2bf(acc[m][n][j]);
                }
        return;
    }

    u16* outp = (z == 0) ? q2 : k2;
    // fold 1/sqrt(64) AND log2(e) into Q so softmax can use native exp2
    const float qscale = (z == 0) ? 0.125f * 1.44269504088896340736f : 1.0f;
    const int head = (n0 + wc * 64) >> 6;
#pragma unroll
    for (int m = 0; m < 4; m++)
#pragma unroll
        for (int n = 0; n < 4; n++) {
            const int dh = n * 16 + l15;
            const int pairi = dh >> 1;
            const bool even = (dh & 1) == 0;
#pragma unroll
            for (int j = 0; j < 4; j++) {
                int srow = m0 + wr * 64 + m * 16 + lhi * 4 + j;
                float v = acc[m][n][j];
                float pv = __shfl_xor(v, 1);
                int pos = tp[srow];
                float cc = cost[(size_t)pos * 32 + pairi];
                float ss = sint[(size_t)pos * 32 + pairi];
                float e = even ? v : pv;
                float o = even ? pv : v;
                float res = (even ? (e * cc - o * ss) : (e * ss + o * cc)) * qscale;
                u16 hb = f2bf(res);
                u16 lb = f2bf(res - bf2f(hb));
                size_t base = ((size_t)head * S_LEN + srow) * 128 + dh;
                outp[base] = hb;
                outp[base + 64] = lb;
            }
        }
}

// ---------------- Flash attention: paired q-tiles + LDS K/V dbuf; base-2 softmax ----------------
#define PLD32 33
__global__ __launch_bounds__(256) void attn_kernel(const u16* __restrict__ q2,
                                                   const u16* __restrict__ k2,
                                                   const u16* __restrict__ vtb,
                                                   u16* __restrict__ attnb) {
    const int h = blockIdx.y;
    const int p = blockIdx.x;              // pair id 0..15 -> tiles (31-p, p)
    const int wid = threadIdx.x >> 6;
    const int lane = threadIdx.x & 63;
    const int l15 = lane & 15, lhi = lane >> 4;

    const u16* Qh2 = q2 + (size_t)h * S_LEN * 128;
    const u16* Kh2 = k2 + (size_t)h * S_LEN * 128;
    const u16* Vh  = vtb + (size_t)h * 64 * S_LEN;

    __shared__ u16 sK[2][64 * 128];
    __shared__ u16 sV[2][64 * 64];
    __shared__ unsigned pls[4][32 * PLD32];
    unsigned* myP = pls[wid];

    const int tileA = 31 - p, tileB = p;
    const int eA = 2 * tileA + 2, eB = 2 * tileB + 2;
    const int etot = eA + eB;              // 66 for every block

    auto stage = [&](int t, int b) {
        const int k = (t < eA) ? t : (t - eA);
        const int k0 = k * 64;
#pragma unroll
        for (int i = 0; i < 4; i++) {
            const int rbase = wid * 16 + i * 4;
            const int row = rbase + (lane >> 4);
            const int cb = (lane & 15) * 16;
            const int csw = cb ^ ((row & 7) << 4);
            gload16(Kh2 + (size_t)(k0 + row) * 128 + (csw >> 1), &sK[b][rbase * 128]);
        }
#pragma unroll
        for (int i = 0; i < 2; i++) {
            const int rbase = wid * 16 + i * 8;
            const int row = rbase + (lane >> 3);
            const int cb = (lane & 7) * 16;
            const int csw = cb ^ ((row & 7) << 4);
            gload16(Vh + (size_t)row * S_LEN + k0 + (csw >> 1), &sV[b][rbase * 64]);
        }
    };

    bf16x8 qhf[2][2], qlf[2][2];
    f32x4 oT[2][4];
    float m_run[2], l_run[2];
    int q0 = 0, my_nkb = 0;

    auto initPass = [&](int tile) {
        q0 = tile * 128 + wid * 32;
        my_nkb = ((q0 + 31) >> 6) + 1;
#pragma unroll
        for (int g = 0; g < 2; g++)
#pragma unroll
            for (int ks = 0; ks < 2; ks++) {
                const u16* qp = Qh2 + (size_t)(q0 + g * 16 + l15) * 128 + ks * 32 + 8 * lhi;
                qhf[g][ks] = *(const bf16x8*)(qp);
                qlf[g][ks] = *(const bf16x8*)(qp + 64);
            }
#pragma unroll
        for (int g = 0; g < 2; g++) {
            m_run[g] = -1e30f;
            l_run[g] = 0.f;
#pragma unroll
            for (int m = 0; m < 4; m++) oT[g][m] = (f32x4){0.f, 0.f, 0.f, 0.f};
        }
    };

    auto writeOut = [&]() {
#pragma unroll
        for (int g = 0; g < 2; g++) {
            const int srow = q0 + g * 16 + l15;
            const float inv = 1.0f / l_run[g];
#pragma unroll
            for (int m = 0; m < 4; m++)
#pragma unroll
                for (int j = 0; j < 4; j++)
                    attnb[(size_t)srow * 1024 + h * 64 + m * 16 + lhi * 4 + j] =
                        f2bf(oT[g][m][j] * inv);
        }
    };

    stage(0, 0);
    initPass(tileA);
    __syncthreads();

    int cur = 0;
    for (int t = 0; t < etot; ++t) {
        if (t + 1 < etot) stage(t + 1, cur ^ 1);
        if (t == eA) { writeOut(); initPass(tileB); }
        const int k = (t < eA) ? t : (t - eA);
        if (k < my_nkb) {
            const int k0 = k * 64;
            bf16x8 kh[4][2], kl[4][2], vfr[4][2];
#pragma unroll
            for (int m = 0; m < 4; m++) {
                const int r = m * 16 + l15;
                const int sw = (r & 7) << 4;
                const u16* kp = &sK[cur][r * 128];
                const u16* vp = &sV[cur][r * 64];
#pragma unroll
                for (int c = 0; c < 2; c++) {
                    kh[m][c] = *(const bf16x8*)(kp + (((c * 64 + lhi * 16) ^ sw) >> 1));
                    kl[m][c] = *(const bf16x8*)(kp + (((128 + c * 64 + lhi * 16) ^ sw) >> 1));
                    vfr[m][c] = *(const bf16x8*)(vp + (((c * 64 + lhi * 16) ^ sw) >> 1));
                }
            }
            f32x4 sT[4][2];
#pragma unroll
            for (int m = 0; m < 4; m++)
#pragma unroll
                for (int g = 0; g < 2; g++) {
                    f32x4 a = (f32x4){0.f, 0.f, 0.f, 0.f};
                    a = __builtin_amdgcn_mfma_f32_16x16x32_bf16(kh[m][0], qlf[g][0], a, 0, 0, 0);
                    a = __builtin_amdgcn_mfma_f32_16x16x32_bf16(kh[m][1], qlf[g][1], a, 0, 0, 0);
                    a = __builtin_amdgcn_mfma_f32_16x16x32_bf16(kl[m][0], qhf[g][0], a, 0, 0, 0);
                    a = __builtin_amdgcn_mfma_f32_16x16x32_bf16(kl[m][1], qhf[g][1], a, 0, 0, 0);
                    a = __builtin_amdgcn_mfma_f32_16x16x32_bf16(kh[m][0], qhf[g][0], a, 0, 0, 0);
                    a = __builtin_amdgcn_mfma_f32_16x16x32_bf16(kh[m][1], qhf[g][1], a, 0, 0, 0);
                    sT[m][g] = a;
                }
            const bool last = (k == my_nkb - 1);
#pragma unroll
            for (int g = 0; g < 2; g++) {
                const int qg = q0 + g * 16 + l15;
                if (last) {
#pragma unroll
                    for (int m = 0; m < 4; m++)
#pragma unroll
                        for (int j = 0; j < 4; j++) {
                            int kg = k0 + m * 16 + lhi * 4 + j;
                            if (kg > qg) sT[m][g][j] = -1e30f;
                        }
                }
                float t0 = fmaxf(fmaxf(sT[0][g][0], sT[0][g][1]), fmaxf(sT[0][g][2], sT[0][g][3]));
                float t1 = fmaxf(fmaxf(sT[1][g][0], sT[1][g][1]), fmaxf(sT[1][g][2], sT[1][g][3]));
                float t2 = fmaxf(fmaxf(sT[2][g][0], sT[2][g][1]), fmaxf(sT[2][g][2], sT[2][g][3]));
                float t3 = fmaxf(fmaxf(sT[3][g][0], sT[3][g][1]), fmaxf(sT[3][g][2], sT[3][g][3]));
                float mx = fmaxf(fmaxf(t0, t1), fmaxf(t2, t3));
                mx = fmaxf(mx, __shfl_xor(mx, 16));
                mx = fmaxf(mx, __shfl_xor(mx, 32));
                float mn = fmaxf(m_run[g], mx);
                float alpha = exp2f(m_run[g] - mn);   // base-2 softmax (log2e folded into Q)
                float s0 = 0.f, s1 = 0.f, s2 = 0.f, s3 = 0.f;
#pragma unroll
                for (int m = 0; m < 4; m++) {
                    float p0 = exp2f(sT[m][g][0] - mn);
                    float p1 = exp2f(sT[m][g][1] - mn);
                    float p2 = exp2f(sT[m][g][2] - mn);
                    float p3 = exp2f(sT[m][g][3] - mn);
                    sT[m][g][0] = p0; sT[m][g][1] = p1; sT[m][g][2] = p2; sT[m][g][3] = p3;
                    s0 += p0; s1 += p1; s2 += p2; s3 += p3;
                }
                float rs = (s0 + s1) + (s2 + s3);
                rs += __shfl_xor(rs, 16);
                rs += __shfl_xor(rs, 32);
                l_run[g] = l_run[g] * alpha + rs;
                m_run[g] = mn;
#pragma unroll
                for (int m = 0; m < 4; m++) {
                    oT[g][m][0] *= alpha; oT[g][m][1] *= alpha;
                    oT[g][m][2] *= alpha; oT[g][m][3] *= alpha;
                }
#pragma unroll
                for (int m = 0; m < 4; m++)
#pragma unroll
                    for (int jj = 0; jj < 2; jj++) {
                        unsigned pk = (unsigned)f2bf(sT[m][g][2 * jj]) |
                                      ((unsigned)f2bf(sT[m][g][2 * jj + 1]) << 16);
                        myP[(g * 16 + l15) * PLD32 + m * 8 + lhi * 2 + jj] = pk;
                    }
            }
            bf16x8 pf[2][2];
#pragma unroll
            for (int g = 0; g < 2; g++)
#pragma unroll
                for (int ks = 0; ks < 2; ks++) {
                    uint4v pw = *(const uint4v*)(myP + (g * 16 + l15) * PLD32 + ks * 16 + 4 * lhi);
                    pf[g][ks] = __builtin_bit_cast(bf16x8, pw);
                }
#pragma unroll
            for (int g = 0; g < 2; g++)
#pragma unroll
                for (int m = 0; m < 4; m++) {
                    oT[g][m] = __builtin_amdgcn_mfma_f32_16x16x32_bf16(vfr[m][0], pf[g][0], oT[g][m], 0, 0, 0);
                    oT[g][m] = __builtin_amdgcn_mfma_f32_16x16x32_bf16(vfr[m][1], pf[g][1], oT[g][m], 0, 0, 0);
                }
        }
        __syncthreads();
        cur ^= 1;
    }
    writeOut();
}

// ---------------- output projection: bf16 x bf16 -> fp32, dbuf gload16-staged ----------------
__global__ __launch_bounds__(256) void gemm_out_kernel(const u16* __restrict__ attnb,
                                                       const u16* __restrict__ woh,
                                                       float* __restrict__ out) {
    __shared__ u16 sA[2][128 * 32];
    __shared__ u16 sB[2][128 * 32];
    const int m0 = blockIdx.y * 128, n0 = blockIdx.x * 128;
    const int tid = threadIdx.x;
    const int lane = tid & 63, wid = tid >> 6;
    const int wr = wid >> 1, wc = wid & 1;
    const int l15 = lane & 15, lhi = lane >> 4;

    f32x4 acc[4][4];
#pragma unroll
    for (int i = 0; i < 4; i++)
#pragma unroll
        for (int j = 0; j < 4; j++) acc[i][j] = (f32x4){0.f, 0.f, 0.f, 0.f};

    auto stageT = [&](int kt, int b) {
#pragma unroll
        for (int i = 0; i < 2; i++) {
            const int rbase = wid * 32 + i * 16;
            const int row = rbase + (lane >> 2);
            gload16(attnb + (size_t)(m0 + row) * 1024 + kt + (lane & 3) * 8, sA[b] + rbase * 32);
            gload16(woh + (size_t)(n0 + row) * 1024 + kt + (lane & 3) * 8, sB[b] + rbase * 32);
        }
    };

    stageT(0, 0);
    __syncthreads();

    int buf = 0;
    for (int kt = 0; kt < 1024; kt += 32, buf ^= 1) {
        if (kt + 32 < 1024) stageT(kt + 32, buf ^ 1);
        bf16x8 af[4], bfr[4];
#pragma unroll
        for (int m = 0; m < 4; m++) {
            int row = wr * 64 + m * 16 + l15;
            af[m] = *(const bf16x8*)(sA[buf] + row * 32 + 8 * lhi);
        }
#pragma unroll
        for (int n = 0; n < 4; n++) {
            int row = wc * 64 + n * 16 + l15;
            bfr[n] = *(const bf16x8*)(sB[buf] + row * 32 + 8 * lhi);
        }
#pragma unroll
        for (int m = 0; m < 4; m++)
#pragma unroll
            for (int n = 0; n < 4; n++)
                acc[m][n] = __builtin_amdgcn_mfma_f32_16x16x32_bf16(af[m], bfr[n], acc[m][n], 0, 0, 0);
        __syncthreads();
    }

#pragma unroll
    for (int m = 0; m < 4; m++)
#pragma unroll
        for (int n = 0; n < 4; n++)
#pragma unroll
            for (int j = 0; j < 4; j++) {
                int srow = m0 + wr * 64 + m * 16 + lhi * 4 + j;
                int eg = n0 + wc * 64 + n * 16 + l15;
                out[(size_t)srow * 1024 + eg] = acc[m][n][j];
            }
}

// ---------------- host launch ----------------
extern "C" void kernel_launch(void* const* d_in, const int* in_sizes, int n_in,
                              void* d_out, int out_size, void* d_ws, size_t ws_size,
                              hipStream_t stream) {
    const float* x = (const float*)d_in[0];
    const int* tp = (const int*)d_in[1];
    const float* wq = (const float*)d_in[2];
    const float* wk = (const float*)d_in[3];
    const float* wv = (const float*)d_in[4];
    const float* wo = (const float*)d_in[5];
    float* out = (float*)d_out;
    char* ws = (char*)d_ws;

    u16* Q2    = (u16*)(ws + 0);           // 16 MiB bf16 [16][4096][128] hi/lo, Q scaled log2e/8
    u16* K2    = (u16*)(ws + 16777216);    // 16 MiB
    u16* VTB   = (u16*)(ws + 33554432);    // 8 MiB bf16 [h*64+dh][4096]
    u16* ATTNB = (u16*)(ws + 41943040);    // 8 MiB bf16 [4096][1024]
    float* COST = (float*)(ws + 50331648); // 512 KiB
    float* SINT = (float*)(ws + 50855936); // 512 KiB
    u16* XH  = (u16*)(ws + 51380224);      // 8 MiB bf16 [4096][1024]
    u16* XL  = (u16*)(ws + 59768832);      // 8 MiB
    u16* WH3 = (u16*)(ws + 68157440);      // 6 MiB bf16 [3][1024][1024]
    u16* WL3 = (u16*)(ws + 74448896);      // 6 MiB
    u16* WOH = (u16*)(ws + 80740352);      // 2 MiB bf16 [1024][1024]

    rope_table_kernel<<<512, 256, 0, stream>>>(COST, SINT);

    split_kernel<<<4096, 256, 0, stream>>>(x, XH, XL, 1048576);
    split_kernel<<<1024, 256, 0, stream>>>(wq, WH3,            WL3,            262144);
    split_kernel<<<1024, 256, 0, stream>>>(wk, WH3 + 1048576,  WL3 + 1048576,  262144);
    split_kernel<<<1024, 256, 0, stream>>>(wv, WH3 + 2097152,  WL3 + 2097152,  262144);
    split_kernel<<<1024, 256, 0, stream>>>(wo, WOH,            (u16*)nullptr,  262144);

    gemm_qkv_kernel<<<dim3(8, 32, 3), 256, 0, stream>>>(
        XH, XL, WH3, WL3, tp, COST, SINT, Q2, K2, VTB);

    attn_kernel<<<dim3(16, 16), 256, 0, stream>>>(Q2, K2, VTB, ATTNB);

    gemm_out_kernel<<<dim3(8, 32), 256, 0, stream>>>(ATTNB, WOH, out);
}